// Round 7
// baseline (346.897 us; speedup 1.0000x reference)
//
#include <hip/hip_runtime.h>
#include <hip/hip_bf16.h>
#include <stdint.h>

// GWNN: out = L2(relu(L1(x))),  L(x) = W_wav · diag(f) · W_inv · (x·W)
// R7: big GEMMs (8192x128x8192) as split-K-by-BLOCKS: grid (M/32, 2), each
// block runs the proven R2 pipeline on half of K with its OWN barriers.
// LDS 72KB -> 2 independent blocks/CU: when one block stalls at vmcnt/barrier
// the other issues (true TLP, unlike R6's shared-barrier convoy).
// f32 partials P[2][M][128] in ws; tiny fused reduce kernels (scale/relu/
// transpose/cvt) produce the layer outputs.

typedef __attribute__((ext_vector_type(4))) float f32x4;
typedef __attribute__((ext_vector_type(8))) short s16x8;
typedef __attribute__((ext_vector_type(4))) short s16x4;

#define DEVI static __device__ __forceinline__

DEVI short bf1(float x){ __bf16 h = (__bf16)x; return __builtin_bit_cast(short, h); }

DEVI s16x8 cvt8(f32x4 lo, f32x4 hi){
  s16x8 r;
#pragma unroll
  for (int i = 0; i < 4; ++i){ r[i] = bf1(lo[i]); r[4+i] = bf1(hi[i]); }
  return r;
}

DEVI void glds16(const void* g, void* l){
  __builtin_amdgcn_global_load_lds((const __attribute__((address_space(1))) void*)g,
                                   (__attribute__((address_space(3))) void*)l, 16, 0, 0);
}

template<int N> DEVI void waitvm(){
  if constexpr (N == 0)      asm volatile("s_waitcnt vmcnt(0)" ::: "memory");
  else if constexpr (N == 5) asm volatile("s_waitcnt vmcnt(5)" ::: "memory");
  else if constexpr (N == 6) asm volatile("s_waitcnt vmcnt(6)" ::: "memory");
}

// ============================================================================
// Split-K big GEMM: P[kh][M][128] += A[M, kh-half of K] @ Bt[128, same]^T
// A fp32 row-major (cvt->bf16 at LDS read). Bt bf16 row-major [128][K].
// One block = 256 thr / 4 waves, BM=32, NBUF=3 ring, counted vmcnt,
// one barrier per step. 72KB LDS -> 2 blocks/CU.
// ============================================================================
__global__ __launch_bounds__(256, 2) void gemm_sk(
    const float* __restrict__ Ap, const short* __restrict__ Btp,
    float* __restrict__ Pp, int K, int M)
{
  constexpr int BM = 32, BN = 128, BK = 64;
  constexpr int ASZ = BM*BK*4;    // 8 KB fp32 A tile
  constexpr int BSZ = BN*BK*2;    // 16 KB
  constexpr int TSZ = ASZ + BSZ;  // 24 KB
  constexpr int NL  = 6;
  constexpr int NBUF = 3, PRE = 2;
  __shared__ uint8_t lds[NBUF*TSZ];   // 72 KB

  const int tid  = threadIdx.x;
  const int lane = tid & 63;
  const int wv   = tid >> 6;
  const int la   = lane & 15;
  const int g4   = lane >> 4;
  const int m0   = blockIdx.x * BM;
  const int kh   = blockIdx.y;
  const int K2   = K >> 1;
  const size_t kb = (size_t)kh * K2;

  const float* Af = Ap;
  int r0 = (wv<<3) + (lane>>4);
  int r1 = r0 + 4;
  const float* gA0 = Af + (size_t)(m0+r0)*K + kb + (((lane&15)^(r0&15))<<2);
  const float* gA1 = Af + (size_t)(m0+r1)*K + kb + (((lane&15)^(r1&15))<<2);
  const int nb0 = (wv<<5) + (lane>>3);
  const short* gB0 = Btp + (size_t)(nb0    )*K + kb + (((lane&7)^(nb0&7))<<3);
  const short* gB1 = Btp + (size_t)(nb0+ 8 )*K + kb + (((lane&7)^(nb0&7))<<3);
  const short* gB2 = Btp + (size_t)(nb0+16 )*K + kb + (((lane&7)^(nb0&7))<<3);
  const short* gB3 = Btp + (size_t)(nb0+24 )*K + kb + (((lane&7)^(nb0&7))<<3);

  int aoff[2][2][2];   // [mi][kf][part] fp32 rows = 16 x 16B units
  int boff[2][2];
#pragma unroll
  for (int mi = 0; mi < 2; ++mi){
    const int r = mi*16 + la;
#pragma unroll
    for (int kf = 0; kf < 2; ++kf){
      const int v0 = kf*8 + (g4<<1);
      aoff[mi][kf][0] = r*256 + (((v0  )^(r&15))<<4);
      aoff[mi][kf][1] = r*256 + (((v0+1)^(r&15))<<4);
    }
  }
#pragma unroll
  for (int ni = 0; ni < 2; ++ni){
    const int n = (wv<<5) + ni*16 + la;
#pragma unroll
    for (int kf = 0; kf < 2; ++kf){
      const int u = kf*4 + g4;
      boff[ni][kf] = n*128 + ((u^(n&7))<<4);
    }
  }

  f32x4 acc[2][2] = {};

  auto STAGE = [&](uint8_t* buf){
    uint8_t* Ab = buf;
    uint8_t* Bb = buf + ASZ;
    glds16(gA0, Ab + (wv<<11));
    glds16(gA1, Ab + (wv<<11) + 1024);
    gA0 += BK; gA1 += BK;
    glds16(gB0, Bb + (wv<<12));
    glds16(gB1, Bb + (wv<<12) + 1024);
    glds16(gB2, Bb + (wv<<12) + 2048);
    glds16(gB3, Bb + (wv<<12) + 3072);
    gB0 += BK; gB1 += BK; gB2 += BK; gB3 += BK;
  };

  auto COMPUTE = [&](const uint8_t* buf){
    const uint8_t* Ab = buf;
    const uint8_t* Bb = buf + ASZ;
#pragma unroll
    for (int kf = 0; kf < 2; ++kf){
      s16x8 a0 = cvt8(*(const f32x4*)(Ab + aoff[0][kf][0]), *(const f32x4*)(Ab + aoff[0][kf][1]));
      s16x8 a1 = cvt8(*(const f32x4*)(Ab + aoff[1][kf][0]), *(const f32x4*)(Ab + aoff[1][kf][1]));
      s16x8 b0 = *(const s16x8*)(Bb + boff[0][kf]);
      s16x8 b1 = *(const s16x8*)(Bb + boff[1][kf]);
      acc[0][0] = __builtin_amdgcn_mfma_f32_16x16x32_bf16(a0, b0, acc[0][0], 0, 0, 0);
      acc[0][1] = __builtin_amdgcn_mfma_f32_16x16x32_bf16(a0, b1, acc[0][1], 0, 0, 0);
      acc[1][0] = __builtin_amdgcn_mfma_f32_16x16x32_bf16(a1, b0, acc[1][0], 0, 0, 0);
      acc[1][1] = __builtin_amdgcn_mfma_f32_16x16x32_bf16(a1, b1, acc[1][1], 0, 0, 0);
    }
  };

  const int nsteps = K2 >> 6;
  uint8_t* const lend = lds + NBUF*TSZ;
  uint8_t* bs = lds;
  uint8_t* bc = lds;
  for (int s = 0; s < PRE && s < nsteps; ++s){
    STAGE(bs);
    bs += TSZ; if (bs == lend) bs = lds;
  }
  for (int t = 0; t < nsteps; ++t){
    if (t < nsteps - 1) waitvm<NL>();
    else                waitvm<0>();
    __builtin_amdgcn_s_barrier();
    asm volatile("" ::: "memory");
    if (t + PRE < nsteps){
      STAGE(bs);
      bs += TSZ; if (bs == lend) bs = lds;
    }
    COMPUTE(bc);
    bc += TSZ; if (bc == lend) bc = lds;
    asm volatile("" ::: "memory");
  }

  // partial epilogue: f32 P[kh][M][128]
  float* P = Pp + (size_t)kh * M * 128;
  const int mbase = m0 + (g4<<2);
  const int nc0   = (wv<<5) + la;
#pragma unroll
  for (int mi = 0; mi < 2; ++mi)
#pragma unroll
    for (int ni = 0; ni < 2; ++ni)
#pragma unroll
      for (int r = 0; r < 4; ++r)
        P[(size_t)(mbase + (mi<<4) + r)*128 + nc0 + (ni<<4)] = acc[mi][ni][r];
}

// ============================================================================
// Non-split GEMM for the small K=128 layers (unchanged R5 structure).
// C[M,128] = A[M,128] @ Bt[128,128]^T, OUT = bf16 transposed [128][M].
// ============================================================================
template<bool ABF>
__global__ __launch_bounds__(256, 1) void gemm_k(
    const void* __restrict__ Ap, const short* __restrict__ Btp,
    void* __restrict__ Outp, int K, int M)
{
  constexpr int BM = 32, BN = 128, BK = 64;
  constexpr int ASZ = ABF ? BM*BK*2 : BM*BK*4;
  constexpr int BSZ = BN*BK*2;
  constexpr int TSZ = ASZ + BSZ;
  constexpr int NL  = ABF ? 5 : 6;
  constexpr int NBUF = 3, PRE = 2;
  __shared__ uint8_t lds[NBUF*TSZ];

  const int tid  = threadIdx.x;
  const int lane = tid & 63;
  const int wv   = tid >> 6;
  const int la   = lane & 15;
  const int g4   = lane >> 4;
  const int m0   = blockIdx.x * BM;

  const float* gA0 = nullptr; const float* gA1 = nullptr; const short* gAh = nullptr;
  if constexpr (!ABF){
    const float* Af = (const float*)Ap;
    int r0 = (wv<<3) + (lane>>4);
    int r1 = r0 + 4;
    gA0 = Af + (size_t)(m0+r0)*K + (((lane&15)^(r0&15))<<2);
    gA1 = Af + (size_t)(m0+r1)*K + (((lane&15)^(r1&15))<<2);
  } else {
    const short* Ah = (const short*)Ap;
    int r = (wv<<3) + (lane>>3);
    gAh = Ah + (size_t)(m0+r)*K + (((lane&7)^(r&7))<<3);
  }
  const int nb0 = (wv<<5) + (lane>>3);
  const short* gB0 = Btp + (size_t)(nb0    )*K + (((lane&7)^(nb0&7))<<3);
  const short* gB1 = Btp + (size_t)(nb0+ 8 )*K + (((lane&7)^(nb0&7))<<3);
  const short* gB2 = Btp + (size_t)(nb0+16 )*K + (((lane&7)^(nb0&7))<<3);
  const short* gB3 = Btp + (size_t)(nb0+24 )*K + (((lane&7)^(nb0&7))<<3);

  int aoff[2][2][2];
  int boff[2][2];
#pragma unroll
  for (int mi = 0; mi < 2; ++mi){
    const int r = mi*16 + la;
#pragma unroll
    for (int kf = 0; kf < 2; ++kf){
      if constexpr (!ABF){
        const int v0 = kf*8 + (g4<<1);
        aoff[mi][kf][0] = r*256 + (((v0  )^(r&15))<<4);
        aoff[mi][kf][1] = r*256 + (((v0+1)^(r&15))<<4);
      } else {
        const int u = kf*4 + g4;
        aoff[mi][kf][0] = r*128 + ((u^(r&7))<<4);
        aoff[mi][kf][1] = 0;
      }
    }
  }
#pragma unroll
  for (int ni = 0; ni < 2; ++ni){
    const int n = (wv<<5) + ni*16 + la;
#pragma unroll
    for (int kf = 0; kf < 2; ++kf){
      const int u = kf*4 + g4;
      boff[ni][kf] = n*128 + ((u^(n&7))<<4);
    }
  }

  f32x4 acc[2][2] = {};

  auto STAGE = [&](uint8_t* buf){
    uint8_t* Ab = buf;
    uint8_t* Bb = buf + ASZ;
    if constexpr (!ABF){
      glds16(gA0, Ab + (wv<<11));
      glds16(gA1, Ab + (wv<<11) + 1024);
      gA0 += BK; gA1 += BK;
    } else {
      glds16(gAh, Ab + (wv<<10));
      gAh += BK;
    }
    glds16(gB0, Bb + (wv<<12));
    glds16(gB1, Bb + (wv<<12) + 1024);
    glds16(gB2, Bb + (wv<<12) + 2048);
    glds16(gB3, Bb + (wv<<12) + 3072);
    gB0 += BK; gB1 += BK; gB2 += BK; gB3 += BK;
  };

  auto COMPUTE = [&](const uint8_t* buf){
    const uint8_t* Ab = buf;
    const uint8_t* Bb = buf + ASZ;
#pragma unroll
    for (int kf = 0; kf < 2; ++kf){
      s16x8 a0, a1, b0, b1;
      if constexpr (!ABF){
        a0 = cvt8(*(const f32x4*)(Ab + aoff[0][kf][0]), *(const f32x4*)(Ab + aoff[0][kf][1]));
        a1 = cvt8(*(const f32x4*)(Ab + aoff[1][kf][0]), *(const f32x4*)(Ab + aoff[1][kf][1]));
      } else {
        a0 = *(const s16x8*)(Ab + aoff[0][kf][0]);
        a1 = *(const s16x8*)(Ab + aoff[1][kf][0]);
      }
      b0 = *(const s16x8*)(Bb + boff[0][kf]);
      b1 = *(const s16x8*)(Bb + boff[1][kf]);
      acc[0][0] = __builtin_amdgcn_mfma_f32_16x16x32_bf16(a0, b0, acc[0][0], 0, 0, 0);
      acc[0][1] = __builtin_amdgcn_mfma_f32_16x16x32_bf16(a0, b1, acc[0][1], 0, 0, 0);
      acc[1][0] = __builtin_amdgcn_mfma_f32_16x16x32_bf16(a1, b0, acc[1][0], 0, 0, 0);
      acc[1][1] = __builtin_amdgcn_mfma_f32_16x16x32_bf16(a1, b1, acc[1][1], 0, 0, 0);
    }
  };

  const int nsteps = K >> 6;
  uint8_t* const lend = lds + NBUF*TSZ;
  uint8_t* bs = lds;
  uint8_t* bc = lds;
  for (int s = 0; s < PRE && s < nsteps; ++s){
    STAGE(bs);
    bs += TSZ; if (bs == lend) bs = lds;
  }
  for (int t = 0; t < nsteps; ++t){
    if (t < nsteps - 1) waitvm<NL>();
    else                waitvm<0>();
    __builtin_amdgcn_s_barrier();
    asm volatile("" ::: "memory");
    if (t + PRE < nsteps){
      STAGE(bs);
      bs += TSZ; if (bs == lend) bs = lds;
    }
    COMPUTE(bc);
    bc += TSZ; if (bc == lend) bc = lds;
    asm volatile("" ::: "memory");
  }

  // epilogue: bf16 transposed [128][M]
  const int mbase = m0 + (g4<<2);
  const int nc0   = (wv<<5) + la;
#pragma unroll
  for (int mi = 0; mi < 2; ++mi){
#pragma unroll
    for (int ni = 0; ni < 2; ++ni){
      s16x4 pk;
#pragma unroll
      for (int r = 0; r < 4; ++r) pk[r] = bf1(acc[mi][ni][r]);
      *(s16x4*)((short*)Outp + (size_t)(nc0 + (ni<<4))*M + (mbase + (mi<<4))) = pk;
    }
  }
}

// ============================================================================
// Reduce kernels: combine K-half partials P[2][M][128] (f32) into layer output.
// ============================================================================

// SPT[n][m] = bf16( f[m] * (P0[m][n] + P1[m][n]) )  — transpose via LDS.
__global__ __launch_bounds__(256) void red_t(
    const float* __restrict__ Pp, const float* __restrict__ fp,
    short* __restrict__ out, int M)
{
  __shared__ short t[128*65];          // [n][m] padded stride 65
  const float* P0 = Pp;
  const float* P1 = Pp + (size_t)M*128;
  const int m0 = blockIdx.x * 64;
  const int tid = threadIdx.x;
#pragma unroll
  for (int it = 0; it < 8; ++it){
    const int idx = it*256 + tid;
    const int m = idx >> 5, nq = idx & 31;
    f32x4 a = ((const f32x4*)(P0 + (size_t)(m0+m)*128))[nq];
    f32x4 b = ((const f32x4*)(P1 + (size_t)(m0+m)*128))[nq];
    const float fv = fp[m0+m];
#pragma unroll
    for (int j = 0; j < 4; ++j)
      t[(nq*4+j)*65 + m] = bf1(fv * (a[j] + b[j]));
  }
  __syncthreads();
#pragma unroll
  for (int it = 0; it < 8; ++it){
    const int idx = it*256 + tid;
    const int n = idx >> 4, mc = idx & 15;
    s16x4 v;
#pragma unroll
    for (int j = 0; j < 4; ++j) v[j] = t[n*65 + mc*4 + j];
    *(s16x4*)(out + (size_t)n*M + m0 + mc*4) = v;
  }
}

// H1[i] = bf16( relu(P0[i] + P1[i]) )  — row-major, fully linear.
__global__ __launch_bounds__(256) void red_r(
    const float* __restrict__ Pp, short* __restrict__ out, int M)
{
  const float* P0 = Pp;
  const float* P1 = Pp + (size_t)M*128;
  const size_t i0 = (size_t)(blockIdx.x*256 + threadIdx.x) * 8;
  f32x4 a0 = ((const f32x4*)(P0 + i0))[0], a1 = ((const f32x4*)(P0 + i0))[1];
  f32x4 b0 = ((const f32x4*)(P1 + i0))[0], b1 = ((const f32x4*)(P1 + i0))[1];
  s16x8 v;
#pragma unroll
  for (int j = 0; j < 4; ++j){
    v[j]   = bf1(fmaxf(a0[j] + b0[j], 0.0f));
    v[4+j] = bf1(fmaxf(a1[j] + b1[j], 0.0f));
  }
  *(s16x8*)(out + i0) = v;
}

// d_out[i] = P0[i] + P1[i]  — f32 row-major, fully linear.
__global__ __launch_bounds__(256) void red_f(
    const float* __restrict__ Pp, float* __restrict__ out, int M)
{
  const float* P0 = Pp;
  const float* P1 = Pp + (size_t)M*128;
  const size_t i0 = (size_t)(blockIdx.x*256 + threadIdx.x) * 4;
  f32x4 a = *(const f32x4*)(P0 + i0);
  f32x4 b = *(const f32x4*)(P1 + i0);
  *(f32x4*)(out + i0) = a + b;
}

// W1T[n][k] = bf16(W1[k][n]), same for W2 — tiny one-shot transpose.
__global__ void wtrans_k(const float* __restrict__ W1, const float* __restrict__ W2,
                         short* __restrict__ T1, short* __restrict__ T2){
  const int idx = blockIdx.x*256 + threadIdx.x;
  const int m = idx >> 14, rem = idx & 16383;
  const int n = rem >> 7, k = rem & 127;
  const float* W = m ? W2 : W1;
  short* T = m ? T2 : T1;
  T[n*128 + k] = bf1(W[k*128 + n]);
}

extern "C" void kernel_launch(void* const* d_in, const int* in_sizes, int n_in,
                              void* d_out, int out_size, void* d_ws, size_t ws_size,
                              hipStream_t stream){
  const float* input = (const float*)d_in[0];
  const float* wav   = (const float*)d_in[1];
  const float* winv  = (const float*)d_in[2];
  const float* W1    = (const float*)d_in[3];
  const float* f1    = (const float*)d_in[4];
  const float* W2    = (const float*)d_in[5];
  const float* f2    = (const float*)d_in[6];

  uint8_t* ws = (uint8_t*)d_ws;
  short* W1T = (short*)(ws);                        // 32 KB
  short* W2T = (short*)(ws + (32<<10));             // 32 KB
  short* XWT = (short*)(ws + (64<<10));             // 2 MB  (x@W transposed bf16)
  short* SPT = (short*)(ws + (64<<10) + (2<<20));   // 2 MB  (filtered spectral, T)
  short* H1  = (short*)(ws + (64<<10) + (4<<20));   // 2 MB  bf16 row-major
  float* P   = (float*)(ws + (64<<10) + (6<<20));   // 8 MB  f32 partials [2][M][128]

  constexpr int M = 8192;
  dim3 b(256);
  dim3 gsk(M/32, 2);     // split-K big GEMM
  dim3 gns(M/32);        // non-split K=128 GEMM
  dim3 grt(M/64);        // red_t
  dim3 grr(M*128/(256*8));   // red_r
  dim3 grf(M*128/(256*4));   // red_f
  dim3 gt(128);

  wtrans_k<<<gt, b, 0, stream>>>(W1, W2, W1T, W2T);
  // layer 1
  gemm_k<false><<<gns, b, 0, stream>>>(input, W1T, XWT, 128, M);
  gemm_sk<<<gsk, b, 0, stream>>>(winv, XWT, P, M, M);
  red_t  <<<grt, b, 0, stream>>>(P, f1, SPT, M);
  gemm_sk<<<gsk, b, 0, stream>>>(wav, SPT, P, M, M);
  red_r  <<<grr, b, 0, stream>>>(P, H1, M);
  // layer 2
  gemm_k<true ><<<gns, b, 0, stream>>>(H1, W2T, XWT, 128, M);
  gemm_sk<<<gsk, b, 0, stream>>>(winv, XWT, P, M, M);
  red_t  <<<grt, b, 0, stream>>>(P, f2, SPT, M);
  gemm_sk<<<gsk, b, 0, stream>>>(wav, SPT, P, M, M);
  red_f  <<<grf, b, 0, stream>>>(P, (float*)d_out, M);
}